// Round 9
// baseline (243.074 us; speedup 1.0000x reference)
//
#include <hip/hip_runtime.h>

#define NFFT 1024
#define TPB 256  // 4 waves per block, one row per wave per iteration
#define RPW 8    // rows per wave, DMA-double-buffered

typedef const __attribute__((address_space(1))) unsigned int gu32;
typedef __attribute__((address_space(3))) unsigned int lu32;

// ---------- complex helpers ----------
__device__ __forceinline__ float2 cmul(float2 a, float2 b) {
  return make_float2(fmaf(a.x, b.x, -a.y * b.y), fmaf(a.x, b.y, a.y * b.x));
}
__device__ __forceinline__ float2 cadd(float2 a, float2 b) { return make_float2(a.x + b.x, a.y + b.y); }
__device__ __forceinline__ float2 csub(float2 a, float2 b) { return make_float2(a.x - b.x, a.y - b.y); }

// y_k = sum_r v_r * e^{-2*pi*i*k*r/4}
__device__ __forceinline__ void dft4(const float2 v[4], float2 y[4]) {
  float2 s02 = cadd(v[0], v[2]), d02 = csub(v[0], v[2]);
  float2 s13 = cadd(v[1], v[3]), d13 = csub(v[1], v[3]);
  y[0] = cadd(s02, s13);
  y[2] = csub(s02, s13);
  y[1] = make_float2(d02.x + d13.y, d02.y - d13.x);  // d02 + (-i)*d13
  y[3] = make_float2(d02.x - d13.y, d02.y + d13.x);  // d02 + (+i)*d13
}

// ---------- DPP quad shuffles ----------
__device__ __forceinline__ float dpp_xor2(float x) {
  return __int_as_float(__builtin_amdgcn_update_dpp(0, __float_as_int(x), 0x4E, 0xF, 0xF, true));
}
__device__ __forceinline__ float dpp_xor1(float x) {
  return __int_as_float(__builtin_amdgcn_update_dpp(0, __float_as_int(x), 0xB1, 0xF, 0xF, true));
}

// ---------- in-lane 16-point FFT (verified r1-r8) ----------
// Output: slot s holds Z[KOF(s)], KOF(s) = (s>>2) | ((s&3)<<2). Twiddles compile-time.
__device__ __forceinline__ void fft16(float2 z[16]) {
  float2 g[16];
  #pragma unroll
  for (int c0 = 0; c0 < 4; ++c0) {
    float2 v[4] = {z[c0], z[c0 + 4], z[c0 + 8], z[c0 + 12]};
    float2 y[4];
    dft4(v, y);
    g[4 * c0 + 0] = y[0]; g[4 * c0 + 1] = y[1]; g[4 * c0 + 2] = y[2]; g[4 * c0 + 3] = y[3];
  }
  const float C1 = 0.92387953251128674f, S1 = 0.38268343236508978f, R = 0.70710678118654752f;
  g[5]  = cmul(g[5],  make_float2( C1, -S1));
  g[6]  = cmul(g[6],  make_float2(  R,  -R));
  g[7]  = cmul(g[7],  make_float2( S1, -C1));
  g[9]  = cmul(g[9],  make_float2(  R,  -R));
  g[10] = make_float2(g[10].y, -g[10].x);
  g[11] = cmul(g[11], make_float2( -R,  -R));
  g[13] = cmul(g[13], make_float2( S1, -C1));
  g[14] = cmul(g[14], make_float2( -R,  -R));
  g[15] = cmul(g[15], make_float2(-C1,  S1));
  #pragma unroll
  for (int k0 = 0; k0 < 4; ++k0) {
    float2 v[4] = {g[k0], g[4 + k0], g[8 + k0], g[12 + k0]};
    float2 y[4];
    dft4(v, y);
    z[4 * k0 + 0] = y[0]; z[4 * k0 + 1] = y[1]; z[4 * k0 + 2] = y[2]; z[4 * k0 + 3] = y[3];
  }
}

// z[sl(k)] *= u^k, k=1..15, sl(k)=((k&3)<<2)|(k>>2). 4 parallel chains (depth 5).
__device__ __forceinline__ void twiddle_apply(float2 z[16], float2 u) {
  const float2 u2 = cmul(u, u);
  const float2 u4 = cmul(u2, u2);
  float2 c1 = u, c2 = u2, c3 = cmul(u2, u), c4 = u4;
  z[4]  = cmul(z[4],  c1); z[8]  = cmul(z[8],  c2);
  z[12] = cmul(z[12], c3); z[1]  = cmul(z[1],  c4);
  c1 = cmul(c1, u4); c2 = cmul(c2, u4); c3 = cmul(c3, u4); c4 = cmul(c4, u4);
  z[5]  = cmul(z[5],  c1); z[9]  = cmul(z[9],  c2);
  z[13] = cmul(z[13], c3); z[2]  = cmul(z[2],  c4);
  c1 = cmul(c1, u4); c2 = cmul(c2, u4); c3 = cmul(c3, u4); c4 = cmul(c4, u4);
  z[6]  = cmul(z[6],  c1); z[10] = cmul(z[10], c2);
  z[14] = cmul(z[14], c3); z[3]  = cmul(z[3],  c4);
  c1 = cmul(c1, u4); c2 = cmul(c2, u4); c3 = cmul(c3, u4);
  z[7]  = cmul(z[7],  c1); z[11] = cmul(z[11], c2); z[15] = cmul(z[15], c3);
}

// Async DMA one 8KB row into wave-private LDS: 8x global_load_lds dwordx4.
// Global source per-lane; LDS dest = uniform base + lane*16 (lane-linear image).
// Cannot be sunk by the compiler (side-effecting), counts in vmcnt.
__device__ __forceinline__ void pref_row(const float4* __restrict__ g, float2* l, int lane) {
  #pragma unroll
  for (int j = 0; j < 8; ++j)
    __builtin_amdgcn_global_load_lds((gu32*)(g + 64 * j + lane),
                                     (lu32*)(l + 128 * j), 16, 0, 0);
}

__global__ __launch_bounds__(TPB, 2) void fft1024_kernel(const float* __restrict__ in,
                                                         float* __restrict__ out,
                                                         int nrows) {
  __shared__ __align__(16) float2 lds[TPB / 64][2][NFFT];  // 2 x 8KB per wave = 64KB/block
  const int wv = threadIdx.x >> 6;
  const int lane = threadIdx.x & 63;
  const long long w = (long long)blockIdx.x * (TPB / 64) + wv;
  const long long r0 = w * RPW;
  if (r0 >= nrows) return;

  const float4* __restrict__ src = reinterpret_cast<const float4*>(in) + r0 * (NFFT / 2);
  float2* __restrict__ dst = reinterpret_cast<float2*>(out) + r0 * NFFT;
  float2* cur = lds[wv][0];
  float2* nxt = lds[wv][1];

  // row-invariant twiddle bases (2 sincos per wave total)
  float sn, cs;
  __sincosf((float)lane * (-6.2831853071795864769f / 1024.0f), &sn, &cs);
  const float2 u1 = make_float2(cs, sn);
  __sincosf((float)(lane & 3) * (-6.2831853071795864769f / 64.0f), &sn, &cs);
  const float2 u2 = make_float2(cs, sn);

  const int m = lane >> 2, p = lane & 3;
  const float sgn1 = (lane & 2) ? -1.0f : 1.0f;
  const float sgn2 = (lane & 1) ? -1.0f : 1.0f;
  const bool tw3 = (p == 3);
  const int kap = lane >> 2;
  const int ur = ((p & 1) << 1) | (p >> 1);  // bitrev2(p)

  pref_row(src, cur, lane);  // row 0 DMA

  #pragma unroll 1  // keep body I$-resident (~6KB); vmcnt selection folds per-branch
  for (int r = 0; r < RPW; ++r) {
    // Issue next row's DMA into the alternate buffer BEFORE waiting: it stays
    // in flight across this row's entire compute (the Little's-law fix).
    if (r + 1 < RPW) pref_row(src + (long long)(r + 1) * (NFFT / 2), nxt, lane);

    // Drain THIS row's 8 DMA ops only (keep-newest counting, in issue order):
    // r==0: newest 8 = pref(1)                    -> vmcnt(8)
    // 0<r<7: newest 24 = stores(r-1)+pref(r+1)    -> vmcnt(24)
    // r==7: newest 16 = stores(6)                 -> vmcnt(16)
    if (r == 0)            { asm volatile("s_waitcnt vmcnt(8)" ::: "memory"); }
    else if (r + 1 < RPW)  { asm volatile("s_waitcnt vmcnt(24)" ::: "memory"); }
    else                   { asm volatile("s_waitcnt vmcnt(16)" ::: "memory"); }
    __builtin_amdgcn_sched_barrier(0);

    // gather FFT mapping from lane-linear row image
    float2 z[16];
    #pragma unroll
    for (int c = 0; c < 16; ++c) z[c] = cur[lane + 64 * c];

    fft16(z);
    twiddle_apply(z, u1);

    // in-place transpose (r3-verified conflict-free XOR swizzle, wave-private)
    #pragma unroll
    for (int s = 0; s < 16; ++s) {
      const int kp = (s >> 2) | ((s & 3) << 2);
      cur[m * 64 + ((p + 4 * kp) ^ ((m & 3) << 2))] = z[s];
    }
    asm volatile("s_waitcnt lgkmcnt(0)" ::: "memory");
    __builtin_amdgcn_sched_barrier(0);
    #pragma unroll
    for (int mm = 0; mm < 16; ++mm) z[mm] = cur[mm * 64 + (lane ^ ((mm & 3) << 2))];
    asm volatile("s_waitcnt lgkmcnt(0)" ::: "memory");  // reads done before this buf's next DMA
    __builtin_amdgcn_sched_barrier(0);

    fft16(z);
    twiddle_apply(z, u2);

    // final radix-4 across quad lanes via DPP
    #pragma unroll
    for (int s = 0; s < 16; ++s) {
      float px = dpp_xor2(z[s].x), py = dpp_xor2(z[s].y);
      float ax = fmaf(sgn1, z[s].x, px), ay = fmaf(sgn1, z[s].y, py);
      float bx = tw3 ? ay : ax;
      float by = tw3 ? -ax : ay;
      float qx = dpp_xor1(bx), qy = dpp_xor1(by);
      z[s].x = fmaf(sgn2, bx, qx);
      z[s].y = fmaf(sgn2, by, qy);
    }

    // store X[kap + 16*t + 256*ur]; per instr: 4 aligned 128B segments
    // (r2-verified: WRITE_SIZE exactly 131072 KB with this pattern)
    float2* __restrict__ orow = dst + (long long)r * NFFT + kap + 256 * ur;
    #pragma unroll
    for (int s = 0; s < 16; ++s) {
      const int t = (s >> 2) | ((s & 3) << 2);
      orow[16 * t] = z[s];
    }

    float2* tmp = cur; cur = nxt; nxt = tmp;  // swap DMA buffers
  }
}

extern "C" void kernel_launch(void* const* d_in, const int* in_sizes, int n_in,
                              void* d_out, int out_size, void* d_ws, size_t ws_size,
                              hipStream_t stream) {
  const float* x = (const float*)d_in[0];
  float* out = (float*)d_out;
  const int rows = in_sizes[0] / (2 * NFFT);      // 16384 rows of 1024 complex
  const int rpb = (TPB / 64) * RPW;               // 32 rows per block
  const int blocks = (rows + rpb - 1) / rpb;      // 512 blocks = 2/CU resident
  fft1024_kernel<<<blocks, TPB, 0, stream>>>(x, out, rows);
}

// Round 16
// 233.239 us; speedup vs baseline: 1.0422x; 1.0422x over previous
//
#include <hip/hip_runtime.h>

#define NFFT 1024
#define TPB 256  // 4 waves per block, one 1024-pt row per wave

// native 16B vector type: __builtin_nontemporal_store requires a native
// vector (HIP's float4 is a class and is rejected by the builtin)
typedef float nfloat4 __attribute__((ext_vector_type(4)));

// ---------- complex helpers ----------
__device__ __forceinline__ float2 cmul(float2 a, float2 b) {
  return make_float2(fmaf(a.x, b.x, -a.y * b.y), fmaf(a.x, b.y, a.y * b.x));
}
__device__ __forceinline__ float2 cadd(float2 a, float2 b) { return make_float2(a.x + b.x, a.y + b.y); }
__device__ __forceinline__ float2 csub(float2 a, float2 b) { return make_float2(a.x - b.x, a.y - b.y); }

// y_k = sum_r v_r * e^{-2*pi*i*k*r/4}
__device__ __forceinline__ void dft4(const float2 v[4], float2 y[4]) {
  float2 s02 = cadd(v[0], v[2]), d02 = csub(v[0], v[2]);
  float2 s13 = cadd(v[1], v[3]), d13 = csub(v[1], v[3]);
  y[0] = cadd(s02, s13);
  y[2] = csub(s02, s13);
  y[1] = make_float2(d02.x + d13.y, d02.y - d13.x);  // d02 + (-i)*d13
  y[3] = make_float2(d02.x - d13.y, d02.y + d13.x);  // d02 + (+i)*d13
}

// ---------- DPP quad shuffles ----------
__device__ __forceinline__ float dpp_xor2(float x) {
  return __int_as_float(__builtin_amdgcn_update_dpp(0, __float_as_int(x), 0x4E, 0xF, 0xF, true));
}
__device__ __forceinline__ float dpp_xor1(float x) {
  return __int_as_float(__builtin_amdgcn_update_dpp(0, __float_as_int(x), 0xB1, 0xF, 0xF, true));
}

// ---------- in-lane 16-point FFT (verified r1-r9) ----------
// Output: slot s holds Z[KOF(s)], KOF(s) = (s>>2) | ((s&3)<<2). Twiddles compile-time.
__device__ __forceinline__ void fft16(float2 z[16]) {
  float2 g[16];
  #pragma unroll
  for (int c0 = 0; c0 < 4; ++c0) {
    float2 v[4] = {z[c0], z[c0 + 4], z[c0 + 8], z[c0 + 12]};
    float2 y[4];
    dft4(v, y);
    g[4 * c0 + 0] = y[0]; g[4 * c0 + 1] = y[1]; g[4 * c0 + 2] = y[2]; g[4 * c0 + 3] = y[3];
  }
  const float C1 = 0.92387953251128674f, S1 = 0.38268343236508978f, R = 0.70710678118654752f;
  g[5]  = cmul(g[5],  make_float2( C1, -S1));
  g[6]  = cmul(g[6],  make_float2(  R,  -R));
  g[7]  = cmul(g[7],  make_float2( S1, -C1));
  g[9]  = cmul(g[9],  make_float2(  R,  -R));
  g[10] = make_float2(g[10].y, -g[10].x);
  g[11] = cmul(g[11], make_float2( -R,  -R));
  g[13] = cmul(g[13], make_float2( S1, -C1));
  g[14] = cmul(g[14], make_float2( -R,  -R));
  g[15] = cmul(g[15], make_float2(-C1,  S1));
  #pragma unroll
  for (int k0 = 0; k0 < 4; ++k0) {
    float2 v[4] = {g[k0], g[4 + k0], g[8 + k0], g[12 + k0]};
    float2 y[4];
    dft4(v, y);
    z[4 * k0 + 0] = y[0]; z[4 * k0 + 1] = y[1]; z[4 * k0 + 2] = y[2]; z[4 * k0 + 3] = y[3];
  }
}

// Multiply slot-ordered spectrum by u^kappa (kappa = KOF(slot)), via running powers.
__device__ __forceinline__ void twiddle_apply(float2 z[16], float2 u) {
  float2 w = u;
  #pragma unroll
  for (int k = 1; k < 16; ++k) {
    const int s = ((k & 3) << 2) | (k >> 2);
    z[s] = cmul(z[s], w);
    w = cmul(w, u);
  }
}

// One wave per 1024-pt row. Global side is pure float4 streaming (1KB/instr);
// FFT lane-mapping is served entirely from LDS with conflict-free swizzles.
// SINGLE CHANGE vs r4 (measured 82us best): output stores are NONTEMPORAL.
// Full 128B-segment NT stores (no RMW) bypass L2/LLC allocation so the input
// stays LLC-resident (r3 showed store allocation evicts it: FETCH 66->138MB).
__global__ __launch_bounds__(TPB, 4) void fft1024_kernel(const float* __restrict__ in,
                                                         float* __restrict__ out,
                                                         int nrows) {
  __shared__ __align__(16) float2 lds[TPB / 64][NFFT];  // 8 KB per wave, wave-private
  const int wv = threadIdx.x >> 6;
  const int lane = threadIdx.x & 63;
  const int row = blockIdx.x * (TPB / 64) + wv;
  if (row >= nrows) return;

  const float4* __restrict__ xin4 = reinterpret_cast<const float4*>(in) + (size_t)row * (NFFT / 2);
  nfloat4* __restrict__ xout4 = reinterpret_cast<nfloat4*>(out) + (size_t)row * (NFFT / 2);
  float2* buf = lds[wv];

  // ---- stage-in: 8x float4 coalesced loads (1KB/instr) -> LDS plain layout
  float4 v4[8];
  #pragma unroll
  for (int j = 0; j < 8; ++j) v4[j] = xin4[lane + 64 * j];
  #pragma unroll
  for (int j = 0; j < 8; ++j)
    *reinterpret_cast<float4*>(&buf[2 * lane + 128 * j]) = v4[j];  // ds_write_b128, conflict-free
  asm volatile("s_waitcnt lgkmcnt(0)" ::: "memory");
  __builtin_amdgcn_sched_barrier(0);

  // ---- gather FFT mapping: z[c] = x[lane + 64c] (contiguous b64 reads)
  float2 z[16];
  #pragma unroll
  for (int c = 0; c < 16; ++c) z[c] = buf[lane + 64 * c];
  asm volatile("s_waitcnt lgkmcnt(0)" ::: "memory");
  __builtin_amdgcn_sched_barrier(0);

  // ---- phase 1
  fft16(z);
  float sn, cs;
  __sincosf((float)lane * (-6.2831853071795864769f / 1024.0f), &sn, &cs);
  twiddle_apply(z, make_float2(cs, sn));

  // ---- transpose (r3-verified conflict-free XOR swizzle, wave-private, no s_barrier)
  const int m = lane >> 2, p = lane & 3;
  #pragma unroll
  for (int s = 0; s < 16; ++s) {
    const int kap = (s >> 2) | ((s & 3) << 2);
    buf[m * 64 + ((p + 4 * kap) ^ ((m & 3) << 2))] = z[s];
  }
  asm volatile("s_waitcnt lgkmcnt(0)" ::: "memory");
  __builtin_amdgcn_sched_barrier(0);
  #pragma unroll
  for (int mm = 0; mm < 16; ++mm) z[mm] = buf[mm * 64 + (lane ^ ((mm & 3) << 2))];
  asm volatile("s_waitcnt lgkmcnt(0)" ::: "memory");
  __builtin_amdgcn_sched_barrier(0);

  // ---- phase 2
  fft16(z);
  __sincosf((float)p * (-6.2831853071795864769f / 64.0f), &sn, &cs);
  twiddle_apply(z, make_float2(cs, sn));

  // ---- final radix-4 across quad lanes via DPP
  const float sgn1 = (lane & 2) ? -1.0f : 1.0f;
  const float sgn2 = (lane & 1) ? -1.0f : 1.0f;
  const bool tw3 = ((lane & 3) == 3);
  #pragma unroll
  for (int s = 0; s < 16; ++s) {
    float px = dpp_xor2(z[s].x), py = dpp_xor2(z[s].y);
    float ax = fmaf(sgn1, z[s].x, px), ay = fmaf(sgn1, z[s].y, py);
    float bx = tw3 ? ay : ax;
    float by = tw3 ? -ax : ay;
    float qx = dpp_xor1(bx), qy = dpp_xor1(by);
    z[s].x = fmaf(sgn2, bx, qx);
    z[s].y = fmaf(sgn2, by, qy);
  }

  // ---- stage-out: write swizzled linear layout, then float4 NT streaming stores.
  // idx = kap + 16t + 256ur (bits [3:0]=kap, [7:4]=t, [9:8]=ur); S(idx)=idx^(ur<<4).
  // Per write instr: residues kap + 16*((t&3)^ur) = 64 distinct -> conflict-free.
  const int kap = lane >> 2;
  const int ur = ((p & 1) << 1) | (p >> 1);  // bitrev2(p)
  const int x16 = ur << 4;
  #pragma unroll
  for (int s = 0; s < 16; ++s) {
    const int t = (s >> 2) | ((s & 3) << 2);
    const int idx = kap + 16 * t + 256 * ur;
    buf[idx ^ x16] = z[s];
  }
  asm volatile("s_waitcnt lgkmcnt(0)" ::: "memory");
  __builtin_amdgcn_sched_barrier(0);
  // reader: i = 2lane+128j -> (i>>8)&3 == j>>1 (const per j); b128 contiguous per instr
  #pragma unroll
  for (int j = 0; j < 8; ++j) {
    nfloat4 w = *reinterpret_cast<const nfloat4*>(&buf[(2 * lane + 128 * j) ^ ((j >> 1) << 4)]);
    __builtin_nontemporal_store(w, xout4 + lane + 64 * j);  // global_store_dwordx4 nt, 1KB/instr
  }
}

extern "C" void kernel_launch(void* const* d_in, const int* in_sizes, int n_in,
                              void* d_out, int out_size, void* d_ws, size_t ws_size,
                              hipStream_t stream) {
  const float* x = (const float*)d_in[0];
  float* out = (float*)d_out;
  const int rows = in_sizes[0] / (2 * NFFT);  // 16384 rows of 1024 complex
  const int rpb = TPB / 64;
  const int blocks = (rows + rpb - 1) / rpb;
  fft1024_kernel<<<blocks, TPB, 0, stream>>>(x, out, rows);
}